// Round 1
// baseline (3031.918 us; speedup 1.0000x reference)
//
#include <hip/hip_runtime.h>
#include <cstddef>

#define THRESH 0.8f
#define DECAY  0.2f

// ---------------------------------------------------------------------------
// Kernel A: fused currents GEMM (x_f @ {w1,w2,w3}^T + b) + spiking recurrence
// + time-mean.  Tile: 64 b x 32 c per block, 256 threads, per-thread 4b x 2c.
// Recurrence state (mem[4], cnt[4] per (b,c)) lives in registers across the
// 5-frame loop; spike is recomputed as (mem > THRESH), exactly matching the
// reference carry semantics (mem0=0 -> spike0=0).
// ---------------------------------------------------------------------------
__global__ __launch_bounds__(256) void spike_kernel(
    const float* __restrict__ state,   // [B,5,512]
    const float* __restrict__ w1, const float* __restrict__ b1,
    const float* __restrict__ w2, const float* __restrict__ b2,
    const float* __restrict__ w3, const float* __restrict__ b3,
    const float* __restrict__ wl, const float* __restrict__ bl,
    float* __restrict__ x)             // [B, 4096], x[b][c*4+k]
{
    __shared__ float As[64][36];        // [b][k] pad->conflict-free
    __shared__ float Ws[3][32][36];     // [j][c][k]

    const int t  = threadIdx.x;
    const int tx = t & 15, ty = t >> 4;
    const int bBase = blockIdx.x * 64;
    const int cBase = blockIdx.y * 32;

    const float wl0 = wl[0], wl1 = wl[1], wl2 = wl[2], bl0 = bl[0];

    float bias[3][2];
#pragma unroll
    for (int ci = 0; ci < 2; ci++) {
        const int c = cBase + tx + ci * 16;
        bias[0][ci] = b1[c]; bias[1][ci] = b2[c]; bias[2][ci] = b3[c];
    }

    float mem[8][4] = {};   // e = bi*2+ci
    float cnt[8][4] = {};
    const float* wjp[3] = {w1, w2, w3};

    for (int f = 0; f < 5; f++) {
        float acc[8][3] = {};
        for (int k0 = 0; k0 < 512; k0 += 32) {
            __syncthreads();
            // stage A: 64x32, coalesced (32 consecutive k per row)
#pragma unroll
            for (int i = 0; i < 8; i++) {
                const int idx = i * 256 + t;
                const int r = idx >> 5, kl = idx & 31;
                As[r][kl] = state[((size_t)(bBase + r) * 5 + f) * 512 + k0 + kl];
            }
            // stage W: 3 x 32 x 32
#pragma unroll
            for (int j = 0; j < 3; j++)
#pragma unroll
                for (int i = 0; i < 4; i++) {
                    const int idx = i * 256 + t;
                    const int r = idx >> 5, kl = idx & 31;
                    Ws[j][r][kl] = wjp[j][(size_t)(cBase + r) * 512 + k0 + kl];
                }
            __syncthreads();
#pragma unroll
            for (int kk = 0; kk < 32; kk += 4) {
                float4 a[4], w[3][2];
#pragma unroll
                for (int bi = 0; bi < 4; bi++)
                    a[bi] = *(const float4*)&As[ty + bi * 16][kk];
#pragma unroll
                for (int j = 0; j < 3; j++)
#pragma unroll
                    for (int ci = 0; ci < 2; ci++)
                        w[j][ci] = *(const float4*)&Ws[j][tx + ci * 16][kk];
#pragma unroll
                for (int bi = 0; bi < 4; bi++)
#pragma unroll
                    for (int ci = 0; ci < 2; ci++) {
                        const int e = bi * 2 + ci;
#pragma unroll
                        for (int j = 0; j < 3; j++)
                            acc[e][j] += a[bi].x * w[j][ci].x + a[bi].y * w[j][ci].y
                                       + a[bi].z * w[j][ci].z + a[bi].w * w[j][ci].w;
                    }
            }
        }
        // 3 recurrence steps (frame repeated 3x, currents constant)
#pragma unroll
        for (int rep = 0; rep < 3; rep++) {
#pragma unroll
            for (int e = 0; e < 8; e++) {
                const int ci = e & 1;
                const float i0 = acc[e][0] + bias[0][ci];
                const float i1 = acc[e][1] + bias[1][ci];
                const float i2 = acc[e][2] + bias[2][ci];
                const float m0 = mem[e][0], m1 = mem[e][1];
                const float m2 = mem[e][2], m3 = mem[e][3];
                const float inner = m0 * wl0 + m1 * wl1 + m2 * wl2 + bl0;
                const float n0 = i0    + ((m0 > THRESH) ? 0.f : DECAY * m0);
                const float n1 = i1    + ((m1 > THRESH) ? 0.f : DECAY * m1);
                const float n2 = i2    + ((m2 > THRESH) ? 0.f : DECAY * m2);
                const float n3 = inner + ((m3 > THRESH) ? 0.f : DECAY * m3);
                mem[e][0] = n0; mem[e][1] = n1; mem[e][2] = n2; mem[e][3] = n3;
                cnt[e][0] += (n0 > THRESH); cnt[e][1] += (n1 > THRESH);
                cnt[e][2] += (n2 > THRESH); cnt[e][3] += (n3 > THRESH);
            }
        }
    }

    const float inv15 = 1.0f / 15.0f;
#pragma unroll
    for (int bi = 0; bi < 4; bi++)
#pragma unroll
        for (int ci = 0; ci < 2; ci++) {
            const int e = bi * 2 + ci;
            const int b = bBase + ty + bi * 16;
            const int c = cBase + tx + ci * 16;
            float4 v = make_float4(cnt[e][0] * inv15, cnt[e][1] * inv15,
                                   cnt[e][2] * inv15, cnt[e][3] * inv15);
            *(float4*)&x[(size_t)b * 4096 + c * 4] = v;
        }
}

// ---------------------------------------------------------------------------
// Generic fp32 GEMM: C[m][n] = act(sum_k A[m][k]*W[n][k] + bias[n])
// 64x64 tile, 256 threads, per-thread 4x4 (interleaved by 16 for bank spread)
// ---------------------------------------------------------------------------
template <bool RELU>
__global__ __launch_bounds__(256) void gemm_kernel(
    const float* __restrict__ A, const float* __restrict__ W,
    const float* __restrict__ bias, float* __restrict__ C,
    int M, int N, int K)
{
    __shared__ float As[64][36];
    __shared__ float Ws[64][36];
    const int t  = threadIdx.x;
    const int tx = t & 15, ty = t >> 4;
    const int mBase = blockIdx.x * 64, nBase = blockIdx.y * 64;

    float acc[4][4] = {};
    for (int k0 = 0; k0 < K; k0 += 32) {
        __syncthreads();
#pragma unroll
        for (int i = 0; i < 8; i++) {
            const int idx = i * 256 + t;
            const int r = idx >> 5, kl = idx & 31;
            As[r][kl] = A[(size_t)(mBase + r) * K + k0 + kl];
            Ws[r][kl] = W[(size_t)(nBase + r) * K + k0 + kl];
        }
        __syncthreads();
#pragma unroll
        for (int kk = 0; kk < 32; kk += 4) {
            float4 a[4], w[4];
#pragma unroll
            for (int i = 0; i < 4; i++) {
                a[i] = *(const float4*)&As[ty + i * 16][kk];
                w[i] = *(const float4*)&Ws[tx + i * 16][kk];
            }
#pragma unroll
            for (int bi = 0; bi < 4; bi++)
#pragma unroll
                for (int ni = 0; ni < 4; ni++)
                    acc[bi][ni] += a[bi].x * w[ni].x + a[bi].y * w[ni].y
                                 + a[bi].z * w[ni].z + a[bi].w * w[ni].w;
        }
    }
#pragma unroll
    for (int ni = 0; ni < 4; ni++) {
        const int n = nBase + tx + ni * 16;
        const float bv = bias[n];
#pragma unroll
        for (int bi = 0; bi < 4; bi++) {
            const int m = mBase + ty + bi * 16;
            float v = acc[bi][ni] + bv;
            if (RELU) v = fmaxf(v, 0.f);
            C[(size_t)m * N + n] = v;
        }
    }
}

// ---------------------------------------------------------------------------
// Head: out[b][n] = (clip?)(sum_k h[b][k]*w[n][k] + bias[n]), N=32, K=1024
// Block: 256 threads = 8 b x 32 n
// ---------------------------------------------------------------------------
template <bool CLIP>
__global__ __launch_bounds__(256) void head_kernel(
    const float* __restrict__ h, const float* __restrict__ w,
    const float* __restrict__ bias, float* __restrict__ out)
{
    const int t = threadIdx.x;
    const int n = t & 31;
    const int b = blockIdx.x * 8 + (t >> 5);
    const float* hr = h + (size_t)b * 1024;
    const float* wr = w + (size_t)n * 1024;
    float s = 0.f;
#pragma unroll 4
    for (int k = 0; k < 1024; k += 4) {
        const float4 hv = *(const float4*)(hr + k);
        const float4 wv = *(const float4*)(wr + k);
        s += hv.x * wv.x + hv.y * wv.y + hv.z * wv.z + hv.w * wv.w;
    }
    s += bias[n];
    if (CLIP) s = fminf(fmaxf(s, -20.f), 2.f);
    out[(size_t)b * 32 + n] = s;
}

// ---------------------------------------------------------------------------
extern "C" void kernel_launch(void* const* d_in, const int* in_sizes, int n_in,
                              void* d_out, int out_size, void* d_ws, size_t ws_size,
                              hipStream_t stream)
{
    const float* state = (const float*)d_in[0];
    const float* w1  = (const float*)d_in[1];  const float* b1  = (const float*)d_in[2];
    const float* w2  = (const float*)d_in[3];  const float* b2  = (const float*)d_in[4];
    const float* w3  = (const float*)d_in[5];  const float* b3  = (const float*)d_in[6];
    const float* wl  = (const float*)d_in[7];  const float* bl  = (const float*)d_in[8];
    const float* w11 = (const float*)d_in[9];  const float* b11 = (const float*)d_in[10];
    const float* w12 = (const float*)d_in[11]; const float* b12 = (const float*)d_in[12];
    const float* w21 = (const float*)d_in[13]; const float* b21 = (const float*)d_in[14];
    const float* w22 = (const float*)d_in[15]; const float* b22 = (const float*)d_in[16];
    const float* wm  = (const float*)d_in[17]; const float* bm  = (const float*)d_in[18];
    const float* ws  = (const float*)d_in[19]; const float* bs  = (const float*)d_in[20];
    float* out = (float*)d_out;

    // workspace: x [2048*4096] + hA [2048*1024] + hB [2048*1024]  (~50.3 MB)
    float* xbuf = (float*)d_ws;
    float* hA = xbuf + (size_t)2048 * 4096;
    float* hB = hA + (size_t)2048 * 1024;

    // spikes + time-mean -> x
    spike_kernel<<<dim3(32, 32), 256, 0, stream>>>(state, w1, b1, w2, b2, w3, b3,
                                                   wl, bl, xbuf);
    // branch 1: mean
    gemm_kernel<true><<<dim3(32, 16), 256, 0, stream>>>(xbuf, w11, b11, hA,
                                                        2048, 1024, 4096);
    gemm_kernel<true><<<dim3(32, 16), 256, 0, stream>>>(hA, w12, b12, hB,
                                                        2048, 1024, 1024);
    head_kernel<false><<<256, 256, 0, stream>>>(hB, wm, bm, out);
    // branch 2: log_std
    gemm_kernel<true><<<dim3(32, 16), 256, 0, stream>>>(xbuf, w21, b21, hA,
                                                        2048, 1024, 4096);
    gemm_kernel<true><<<dim3(32, 16), 256, 0, stream>>>(hA, w22, b22, hB,
                                                        2048, 1024, 1024);
    head_kernel<true><<<256, 256, 0, stream>>>(hB, ws, bs, out + 65536);
}

// Round 2
// 476.369 us; speedup vs baseline: 6.3646x; 6.3646x over previous
//
#include <hip/hip_runtime.h>
#include <cstddef>
#include <cstdint>

#define THRESH 0.8f
#define DECAY  0.2f

typedef unsigned short ushort_t;
typedef __attribute__((ext_vector_type(8))) short bf16x8;
typedef __attribute__((ext_vector_type(4))) float f32x4;

__device__ __forceinline__ ushort_t f2bf(float f) {
    union { float f; unsigned u; } v; v.f = f;
    unsigned r = v.u + 0x7FFFu + ((v.u >> 16) & 1u);
    return (ushort_t)(r >> 16);
}
__device__ __forceinline__ float bf2f(ushort_t h) {
    union { unsigned u; float f; } v; v.u = ((unsigned)h) << 16;
    return v.f;
}
__device__ __forceinline__ float blo(unsigned u) {
    union { unsigned x; float f; } v; v.x = u << 16; return v.f;
}
__device__ __forceinline__ float bhi(unsigned u) {
    union { unsigned x; float f; } v; v.x = u & 0xFFFF0000u; return v.f;
}

// async global->LDS, 16B per lane; LDS dest = wave-uniform base + lane*16
__device__ __forceinline__ void gload16(const void* g, void* l) {
    __builtin_amdgcn_global_load_lds(
        (const __attribute__((address_space(1))) void*)g,
        (__attribute__((address_space(3))) void*)l,
        16, 0, 0);
}

// ---------------------------------------------------------------------------
// MFMA GEMM: C[m][n] = act(sum_k A[m][k]*W[n][k] + bias[n])
// A: [M, lda] bf16 (hi, + lo if NSPLIT>1), W: [N, K] bf16 (hi/lo)
// 128x128 tile, 256 threads = 4 waves (2x2 of 64x64), 16x16x32 MFMA.
// NSPLIT=1: plain bf16. NSPLIT=3: hi*wh + hi*wl + lo*wh (near-fp32).
// aHalfOff: for block-diagonal layer-2 (n-half selects A column offset).
// ---------------------------------------------------------------------------
template <int NSPLIT, bool RELU, bool OUT_BF16>
__global__ __launch_bounds__(256) void mfma_gemm(
    const ushort_t* __restrict__ Ah, const ushort_t* __restrict__ Al,
    const ushort_t* __restrict__ Wh, const ushort_t* __restrict__ Wl,
    const float* __restrict__ bias, void* __restrict__ Cv,
    int N, int K, int lda, int aHalfOff, int ldc)
{
    constexpr int NS = (NSPLIT > 1) ? 2 : 1;
    __shared__ ushort_t sA[NS][128 * 32];
    __shared__ ushort_t sW[NS][128 * 32];

    const int t = threadIdx.x;
    const int mBase = blockIdx.x * 128;
    const int nBase = blockIdx.y * 128;
    const int aOff = (2 * nBase >= N) ? aHalfOff : 0;

    const int lane = t & 63;
    const int wv = t >> 6;
    const int wm = (wv & 1) * 64;
    const int wn = (wv >> 1) * 64;
    const int fr = lane & 15;     // m (A) / n (W) within 16-tile
    const int fq = lane >> 4;     // k-quad: k offset = fq*8

    const int r0 = t >> 2;        // staging row (chunk 0)
    const int cc = (t & 3) * 8;   // staging k-col

    f32x4 acc[4][4];
#pragma unroll
    for (int i = 0; i < 4; i++)
#pragma unroll
        for (int j = 0; j < 4; j++) {
            f32x4 z = {0.f, 0.f, 0.f, 0.f};
            acc[i][j] = z;
        }

    for (int k0 = 0; k0 < K; k0 += 32) {
#pragma unroll
        for (int i = 0; i < 2; i++) {
            const int row = r0 + i * 64;
            const int lin = (i * 256 + t) * 8;
            gload16(&Ah[(size_t)(mBase + row) * lda + aOff + k0 + cc], &sA[0][lin]);
            gload16(&Wh[(size_t)(nBase + row) * K + k0 + cc], &sW[0][lin]);
            if (NS == 2) {
                gload16(&Al[(size_t)(mBase + row) * lda + aOff + k0 + cc], &sA[1][lin]);
                gload16(&Wl[(size_t)(nBase + row) * K + k0 + cc], &sW[1][lin]);
            }
        }
        __syncthreads();

        bf16x8 af[4][NS], wf[4][NS];
#pragma unroll
        for (int i = 0; i < 4; i++)
#pragma unroll
            for (int s = 0; s < NS; s++) {
                af[i][s] = *(const bf16x8*)&sA[s][(wm + i * 16 + fr) * 32 + fq * 8];
                wf[i][s] = *(const bf16x8*)&sW[s][(wn + i * 16 + fr) * 32 + fq * 8];
            }
#pragma unroll
        for (int i = 0; i < 4; i++)
#pragma unroll
            for (int j = 0; j < 4; j++) {
                acc[i][j] = __builtin_amdgcn_mfma_f32_16x16x32_bf16(af[i][0], wf[j][0], acc[i][j], 0, 0, 0);
                if (NSPLIT >= 3) {
                    acc[i][j] = __builtin_amdgcn_mfma_f32_16x16x32_bf16(af[i][0], wf[j][1], acc[i][j], 0, 0, 0);
                    acc[i][j] = __builtin_amdgcn_mfma_f32_16x16x32_bf16(af[i][1], wf[j][0], acc[i][j], 0, 0, 0);
                }
            }
        __syncthreads();
    }

    // epilogue: C/D layout col=lane&15, row=(lane>>4)*4+reg
#pragma unroll
    for (int j = 0; j < 4; j++) {
        const int col = nBase + wn + j * 16 + fr;
        const float bv = bias[col];
#pragma unroll
        for (int i = 0; i < 4; i++)
#pragma unroll
            for (int r = 0; r < 4; r++) {
                const int row = mBase + wm + i * 16 + fq * 4 + r;
                float v = acc[i][j][r] + bv;
                if (RELU) v = fmaxf(v, 0.f);
                if (OUT_BF16)
                    ((ushort_t*)Cv)[(size_t)row * ldc + col] = f2bf(v);
                else
                    ((float*)Cv)[(size_t)row * ldc + col] = v;
            }
    }
}

// ---------------------------------------------------------------------------
// LIF recurrence over 15 steps; cur: [B*5, 3072] fp32 (i1|i2|i3 per channel),
// writes x bf16 [2048, 4096] (col = c*4 + j).
// ---------------------------------------------------------------------------
__global__ __launch_bounds__(256) void recur_kernel(
    const float* __restrict__ cur, const float* __restrict__ wl,
    const float* __restrict__ bl, ushort_t* __restrict__ x)
{
    const int idx = blockIdx.x * 256 + threadIdx.x;
    const int b = idx >> 10, c = idx & 1023;
    const float wl0 = wl[0], wl1 = wl[1], wl2 = wl[2], bl0 = bl[0];
    float m0 = 0, m1 = 0, m2 = 0, m3 = 0;
    float s0 = 0, s1 = 0, s2 = 0, s3 = 0;
#pragma unroll
    for (int f = 0; f < 5; f++) {
        const float* p = cur + (size_t)(b * 5 + f) * 3072 + c;
        const float i1 = p[0], i2 = p[1024], i3 = p[2048];
#pragma unroll
        for (int rep = 0; rep < 3; rep++) {
            const float inner = m0 * wl0 + m1 * wl1 + m2 * wl2 + bl0;
            const float n0 = i1 + ((m0 > THRESH) ? 0.f : DECAY * m0);
            const float n1 = i2 + ((m1 > THRESH) ? 0.f : DECAY * m1);
            const float n2 = i3 + ((m2 > THRESH) ? 0.f : DECAY * m2);
            const float n3 = inner + ((m3 > THRESH) ? 0.f : DECAY * m3);
            m0 = n0; m1 = n1; m2 = n2; m3 = n3;
            s0 += (n0 > THRESH) ? 1.f : 0.f;
            s1 += (n1 > THRESH) ? 1.f : 0.f;
            s2 += (n2 > THRESH) ? 1.f : 0.f;
            s3 += (n3 > THRESH) ? 1.f : 0.f;
        }
    }
    const float inv = 1.f / 15.f;
    ushort4 o;
    o.x = f2bf(s0 * inv); o.y = f2bf(s1 * inv);
    o.z = f2bf(s2 * inv); o.w = f2bf(s3 * inv);
    *(ushort4*)&x[(size_t)b * 4096 + c * 4] = o;
}

// fp32 -> bf16 hi/lo split (float4 vectorized)
__global__ __launch_bounds__(256) void split2v(
    const float4* __restrict__ src, ushort4* __restrict__ hi,
    ushort4* __restrict__ lo, int n4)
{
    const int i = blockIdx.x * 256 + threadIdx.x;
    if (i >= n4) return;
    const float4 v = src[i];
    ushort4 h, l;
    h.x = f2bf(v.x); l.x = f2bf(v.x - bf2f(h.x));
    h.y = f2bf(v.y); l.y = f2bf(v.y - bf2f(h.y));
    h.z = f2bf(v.z); l.z = f2bf(v.z - bf2f(h.z));
    h.w = f2bf(v.w); l.w = f2bf(v.w - bf2f(h.w));
    hi[i] = h; lo[i] = l;
}

// fp32 -> bf16
__global__ __launch_bounds__(256) void cvt1v(
    const float4* __restrict__ src, ushort4* __restrict__ dst, int n4)
{
    const int i = blockIdx.x * 256 + threadIdx.x;
    if (i >= n4) return;
    const float4 v = src[i];
    ushort4 h;
    h.x = f2bf(v.x); h.y = f2bf(v.y); h.z = f2bf(v.z); h.w = f2bf(v.w);
    dst[i] = h;
}

__global__ __launch_bounds__(256) void pack_bias(
    const float* __restrict__ b1, const float* __restrict__ b2,
    const float* __restrict__ b3, const float* __restrict__ b11,
    const float* __restrict__ b21, const float* __restrict__ b12,
    const float* __restrict__ b22, float* __restrict__ b123,
    float* __restrict__ bb1, float* __restrict__ bb2)
{
    const int i = blockIdx.x * 256 + threadIdx.x;
    if (i < 1024) {
        b123[i] = b1[i]; b123[1024 + i] = b2[i]; b123[2048 + i] = b3[i];
        bb1[i] = b11[i]; bb1[1024 + i] = b21[i];
        bb2[i] = b12[i]; bb2[1024 + i] = b22[i];
    }
}

// ---------------------------------------------------------------------------
// Head: out[b][n] = (clip?)(sum_k h_bf16[b][colOff+k]*w[n][k] + bias[n])
// ---------------------------------------------------------------------------
template <bool CLIP>
__global__ __launch_bounds__(256) void head_kernel(
    const ushort_t* __restrict__ h, int colOff, const float* __restrict__ w,
    const float* __restrict__ bias, float* __restrict__ out)
{
    const int t = threadIdx.x;
    const int n = t & 31;
    const int b = blockIdx.x * 8 + (t >> 5);
    const ushort_t* hr = h + (size_t)b * 2048 + colOff;
    const float* wr = w + (size_t)n * 1024;
    float s = 0.f;
#pragma unroll 4
    for (int k = 0; k < 1024; k += 8) {
        const uint4 hv = *(const uint4*)&hr[k];
        const float4 w0 = *(const float4*)&wr[k];
        const float4 w1 = *(const float4*)&wr[k + 4];
        s += blo(hv.x) * w0.x + bhi(hv.x) * w0.y
           + blo(hv.y) * w0.z + bhi(hv.y) * w0.w
           + blo(hv.z) * w1.x + bhi(hv.z) * w1.y
           + blo(hv.w) * w1.z + bhi(hv.w) * w1.w;
    }
    s += bias[n];
    if (CLIP) s = fminf(fmaxf(s, -20.f), 2.f);
    out[(size_t)b * 32 + n] = s;
}

// ---------------------------------------------------------------------------
extern "C" void kernel_launch(void* const* d_in, const int* in_sizes, int n_in,
                              void* d_out, int out_size, void* d_ws, size_t ws_size,
                              hipStream_t stream)
{
    const float* state = (const float*)d_in[0];
    const float* w1  = (const float*)d_in[1];  const float* b1  = (const float*)d_in[2];
    const float* w2  = (const float*)d_in[3];  const float* b2  = (const float*)d_in[4];
    const float* w3  = (const float*)d_in[5];  const float* b3  = (const float*)d_in[6];
    const float* wl  = (const float*)d_in[7];  const float* bl  = (const float*)d_in[8];
    const float* w11 = (const float*)d_in[9];  const float* b11 = (const float*)d_in[10];
    const float* w12 = (const float*)d_in[11]; const float* b12 = (const float*)d_in[12];
    const float* w21 = (const float*)d_in[13]; const float* b21 = (const float*)d_in[14];
    const float* w22 = (const float*)d_in[15]; const float* b22 = (const float*)d_in[16];
    const float* wm  = (const float*)d_in[17]; const float* bm  = (const float*)d_in[18];
    const float* ws  = (const float*)d_in[19]; const float* bs  = (const float*)d_in[20];
    float* out = (float*)d_out;

    // ---- workspace layout (~208 MB) ----
    char* wp = (char*)d_ws;
    float*    cur   = (float*)wp;     wp += (size_t)10240 * 3072 * 4;  // 125.8 MB
    ushort_t* sh    = (ushort_t*)wp;  wp += (size_t)10240 * 512 * 2;
    ushort_t* sl    = (ushort_t*)wp;  wp += (size_t)10240 * 512 * 2;
    ushort_t* wh123 = (ushort_t*)wp;  wp += (size_t)3072 * 512 * 2;
    ushort_t* wl123 = (ushort_t*)wp;  wp += (size_t)3072 * 512 * 2;
    ushort_t* xb    = (ushort_t*)wp;  wp += (size_t)2048 * 4096 * 2;
    ushort_t* w1b   = (ushort_t*)wp;  wp += (size_t)2048 * 4096 * 2;
    ushort_t* w2b   = (ushort_t*)wp;  wp += (size_t)2048 * 1024 * 2;
    ushort_t* h1    = (ushort_t*)wp;  wp += (size_t)2048 * 2048 * 2;
    ushort_t* h2    = (ushort_t*)wp;  wp += (size_t)2048 * 2048 * 2;
    float*    b123  = (float*)wp;     wp += 3072 * 4;
    float*    bb1   = (float*)wp;     wp += 2048 * 4;
    float*    bb2   = (float*)wp;     wp += 2048 * 4;

    // ---- precision prep ----
    split2v<<<5120, 256, 0, stream>>>((const float4*)state, (ushort4*)sh, (ushort4*)sl, 1310720);
    split2v<<<512, 256, 0, stream>>>((const float4*)w1, (ushort4*)wh123, (ushort4*)wl123, 131072);
    split2v<<<512, 256, 0, stream>>>((const float4*)w2, (ushort4*)(wh123 + 524288),
                                     (ushort4*)(wl123 + 524288), 131072);
    split2v<<<512, 256, 0, stream>>>((const float4*)w3, (ushort4*)(wh123 + 1048576),
                                     (ushort4*)(wl123 + 1048576), 131072);
    cvt1v<<<4096, 256, 0, stream>>>((const float4*)w11, (ushort4*)w1b, 1048576);
    cvt1v<<<4096, 256, 0, stream>>>((const float4*)w21, (ushort4*)(w1b + 4194304), 1048576);
    cvt1v<<<1024, 256, 0, stream>>>((const float4*)w12, (ushort4*)w2b, 262144);
    cvt1v<<<1024, 256, 0, stream>>>((const float4*)w22, (ushort4*)(w2b + 1048576), 262144);
    pack_bias<<<4, 256, 0, stream>>>(b1, b2, b3, b11, b21, b12, b22, b123, bb1, bb2);

    // ---- currents GEMM (3-term split): [10240,512] x [3072,512]^T -> cur ----
    mfma_gemm<3, false, false><<<dim3(80, 24), 256, 0, stream>>>(
        sh, sl, wh123, wl123, b123, cur, 3072, 512, 512, 0, 3072);

    // ---- recurrence -> x bf16 [2048, 4096] ----
    recur_kernel<<<8192, 256, 0, stream>>>(cur, wl, bl, xb);

    // ---- MLP layer 1 (both branches, N=2048): x @ [w11||w21]^T, relu ----
    mfma_gemm<1, true, true><<<dim3(16, 16), 256, 0, stream>>>(
        xb, nullptr, w1b, nullptr, bb1, h1, 2048, 4096, 4096, 0, 2048);

    // ---- MLP layer 2 (block-diagonal): h1-half @ [w12||w22]^T, relu ----
    mfma_gemm<1, true, true><<<dim3(16, 16), 256, 0, stream>>>(
        h1, nullptr, w2b, nullptr, bb2, h2, 2048, 1024, 2048, 1024, 2048);

    // ---- heads ----
    head_kernel<false><<<256, 256, 0, stream>>>(h2, 0, wm, bm, out);
    head_kernel<true><<<256, 256, 0, stream>>>(h2, 1024, ws, bs, out + 65536);
}

// Round 3
// 427.148 us; speedup vs baseline: 7.0981x; 1.1152x over previous
//
#include <hip/hip_runtime.h>
#include <cstddef>
#include <cstdint>

#define THRESH 0.8f
#define DECAY  0.2f

typedef unsigned short ushort_t;
typedef __attribute__((ext_vector_type(8))) short bf16x8;
typedef __attribute__((ext_vector_type(4))) float f32x4;

__device__ __forceinline__ ushort_t f2bf(float f) {
    union { float f; unsigned u; } v; v.f = f;
    unsigned r = v.u + 0x7FFFu + ((v.u >> 16) & 1u);
    return (ushort_t)(r >> 16);
}
__device__ __forceinline__ float bf2f(ushort_t h) {
    union { unsigned u; float f; } v; v.u = ((unsigned)h) << 16;
    return v.f;
}
__device__ __forceinline__ float blo(unsigned u) {
    union { unsigned x; float f; } v; v.x = u << 16; return v.f;
}
__device__ __forceinline__ float bhi(unsigned u) {
    union { unsigned x; float f; } v; v.x = u & 0xFFFF0000u; return v.f;
}

// async global->LDS, 16B per lane; LDS dest = wave-uniform base + lane*16
__device__ __forceinline__ void gload16(const void* g, void* l) {
    __builtin_amdgcn_global_load_lds(
        (const __attribute__((address_space(1))) void*)g,
        (__attribute__((address_space(3))) void*)l,
        16, 0, 0);
}

// ---------------------------------------------------------------------------
// 512-thread (8-wave) MFMA GEMM, 128x128 tile, BK=32, 16x16x32 bf16 MFMA.
// Wave wv: wm=(wv&1)*64, wn=(wv>>1)*32 -> per-wave 64x32 (acc[4][2]).
// NSPLIT=1: plain bf16.  NSPLIT=3: hi*wh + hi*wl + lo*wh (near-fp32).
// K is the PER-SLICE length; blockIdx.z selects k-slice and output slice
// (C += z*sliceStride).  bias==nullptr -> raw partial (split-K mode).
// aHalfOff: block-diagonal A column offset for the upper n-half.
// ---------------------------------------------------------------------------
template <int NSPLIT>
__global__ __launch_bounds__(512) void mfma_gemm512(
    const ushort_t* __restrict__ Ah, const ushort_t* __restrict__ Al,
    const ushort_t* __restrict__ Wh, const ushort_t* __restrict__ Wl,
    const float* __restrict__ bias, float* __restrict__ C,
    int N, int K, int lda, int ldw, int ldc, int aHalfOff,
    size_t sliceStride)
{
    constexpr int NS = (NSPLIT > 1) ? 2 : 1;
    __shared__ ushort_t sA[NS][128 * 32];
    __shared__ ushort_t sW[NS][128 * 32];

    const int t = threadIdx.x;
    const int mBase = blockIdx.x * 128;
    const int nBase = blockIdx.y * 128;
    const int kOff = blockIdx.z * K;
    const int aOff = (2 * nBase >= N) ? aHalfOff : 0;
    float* Cz = C + (size_t)blockIdx.z * sliceStride;

    const int lane = t & 63;
    const int wv = t >> 6;
    const int wm = (wv & 1) * 64;
    const int wn = (wv >> 1) * 32;
    const int fr = lane & 15;     // m (A) / n (W) within 16-tile
    const int fq = lane >> 4;     // k-quad: k offset = fq*8

    const int r0 = t >> 2;        // staging row
    const int cc = (t & 3) * 8;   // staging k-col

    f32x4 acc[4][2];
#pragma unroll
    for (int i = 0; i < 4; i++)
#pragma unroll
        for (int j = 0; j < 2; j++) {
            f32x4 z = {0.f, 0.f, 0.f, 0.f};
            acc[i][j] = z;
        }

    for (int k0 = 0; k0 < K; k0 += 32) {
        const int lin = t * 8;
        gload16(&Ah[(size_t)(mBase + r0) * lda + aOff + kOff + k0 + cc], &sA[0][lin]);
        gload16(&Wh[(size_t)(nBase + r0) * ldw + kOff + k0 + cc], &sW[0][lin]);
        if (NS == 2) {
            gload16(&Al[(size_t)(mBase + r0) * lda + aOff + kOff + k0 + cc], &sA[1][lin]);
            gload16(&Wl[(size_t)(nBase + r0) * ldw + kOff + k0 + cc], &sW[1][lin]);
        }
        __syncthreads();

        bf16x8 af[4][NS], wf[2][NS];
#pragma unroll
        for (int s = 0; s < NS; s++) {
#pragma unroll
            for (int i = 0; i < 4; i++)
                af[i][s] = *(const bf16x8*)&sA[s][(wm + i * 16 + fr) * 32 + fq * 8];
#pragma unroll
            for (int j = 0; j < 2; j++)
                wf[j][s] = *(const bf16x8*)&sW[s][(wn + j * 16 + fr) * 32 + fq * 8];
        }
#pragma unroll
        for (int i = 0; i < 4; i++)
#pragma unroll
            for (int j = 0; j < 2; j++) {
                acc[i][j] = __builtin_amdgcn_mfma_f32_16x16x32_bf16(af[i][0], wf[j][0], acc[i][j], 0, 0, 0);
                if (NSPLIT >= 3) {
                    acc[i][j] = __builtin_amdgcn_mfma_f32_16x16x32_bf16(af[i][0], wf[j][1], acc[i][j], 0, 0, 0);
                    acc[i][j] = __builtin_amdgcn_mfma_f32_16x16x32_bf16(af[i][1], wf[j][0], acc[i][j], 0, 0, 0);
                }
            }
        __syncthreads();
    }

    // epilogue: C/D layout col=lane&15, row=(lane>>4)*4+reg
#pragma unroll
    for (int j = 0; j < 2; j++) {
        const int col = nBase + wn + j * 16 + fr;
        const float bv = bias ? bias[col] : 0.f;
#pragma unroll
        for (int i = 0; i < 4; i++)
#pragma unroll
            for (int r = 0; r < 4; r++) {
                const int row = mBase + wm + i * 16 + fq * 4 + r;
                Cz[(size_t)row * ldc + col] = acc[i][j][r] + bv;
            }
    }
}

// ---------------------------------------------------------------------------
// split-K reduce: out_bf16[m][n] = relu(sum_s part[s][m][n] + bias[n])
// vectorized x4; MN = M*N
// ---------------------------------------------------------------------------
template <int S>
__global__ __launch_bounds__(256) void reduce_relu(
    const float* __restrict__ part, const float* __restrict__ bias,
    ushort_t* __restrict__ out, int N, size_t MN)
{
    const size_t i4 = (size_t)blockIdx.x * 256 + threadIdx.x;
    const size_t e = i4 * 4;
    if (e >= MN) return;
    float4 a = *(const float4*)&part[e];
#pragma unroll
    for (int s = 1; s < S; s++) {
        const float4 b = *(const float4*)&part[s * MN + e];
        a.x += b.x; a.y += b.y; a.z += b.z; a.w += b.w;
    }
    const int n = (int)(e & (size_t)(N - 1));
    const float4 bv = *(const float4*)&bias[n];
    ushort4 o;
    o.x = f2bf(fmaxf(a.x + bv.x, 0.f));
    o.y = f2bf(fmaxf(a.y + bv.y, 0.f));
    o.z = f2bf(fmaxf(a.z + bv.z, 0.f));
    o.w = f2bf(fmaxf(a.w + bv.w, 0.f));
    *(ushort4*)&out[e] = o;
}

// ---------------------------------------------------------------------------
// LIF recurrence over 15 steps; cur: [B*5, 3072] fp32 (i1|i2|i3 per channel),
// writes x bf16 [2048, 4096] (col = c*4 + j).
// ---------------------------------------------------------------------------
__global__ __launch_bounds__(256) void recur_kernel(
    const float* __restrict__ cur, const float* __restrict__ wl,
    const float* __restrict__ bl, ushort_t* __restrict__ x)
{
    const int idx = blockIdx.x * 256 + threadIdx.x;
    const int b = idx >> 10, c = idx & 1023;
    const float wl0 = wl[0], wl1 = wl[1], wl2 = wl[2], bl0 = bl[0];
    float m0 = 0, m1 = 0, m2 = 0, m3 = 0;
    float s0 = 0, s1 = 0, s2 = 0, s3 = 0;
#pragma unroll
    for (int f = 0; f < 5; f++) {
        const float* p = cur + (size_t)(b * 5 + f) * 3072 + c;
        const float i1 = p[0], i2 = p[1024], i3 = p[2048];
#pragma unroll
        for (int rep = 0; rep < 3; rep++) {
            const float inner = m0 * wl0 + m1 * wl1 + m2 * wl2 + bl0;
            const float n0 = i1 + ((m0 > THRESH) ? 0.f : DECAY * m0);
            const float n1 = i2 + ((m1 > THRESH) ? 0.f : DECAY * m1);
            const float n2 = i3 + ((m2 > THRESH) ? 0.f : DECAY * m2);
            const float n3 = inner + ((m3 > THRESH) ? 0.f : DECAY * m3);
            m0 = n0; m1 = n1; m2 = n2; m3 = n3;
            s0 += (n0 > THRESH) ? 1.f : 0.f;
            s1 += (n1 > THRESH) ? 1.f : 0.f;
            s2 += (n2 > THRESH) ? 1.f : 0.f;
            s3 += (n3 > THRESH) ? 1.f : 0.f;
        }
    }
    const float inv = 1.f / 15.f;
    ushort4 o;
    o.x = f2bf(s0 * inv); o.y = f2bf(s1 * inv);
    o.z = f2bf(s2 * inv); o.w = f2bf(s3 * inv);
    *(ushort4*)&x[(size_t)b * 4096 + c * 4] = o;
}

// ---------------------------------------------------------------------------
// Consolidated prep: hi/lo splits, bf16 converts, bias packing — one launch.
// ---------------------------------------------------------------------------
__device__ __forceinline__ void do_split(const float4* src, ushort4* hi,
                                         ushort4* lo, int i) {
    const float4 v = src[i];
    ushort4 h, l;
    h.x = f2bf(v.x); l.x = f2bf(v.x - bf2f(h.x));
    h.y = f2bf(v.y); l.y = f2bf(v.y - bf2f(h.y));
    h.z = f2bf(v.z); l.z = f2bf(v.z - bf2f(h.z));
    h.w = f2bf(v.w); l.w = f2bf(v.w - bf2f(h.w));
    hi[i] = h; lo[i] = l;
}
__device__ __forceinline__ void do_cvt(const float4* src, ushort4* dst, int i) {
    const float4 v = src[i];
    ushort4 h;
    h.x = f2bf(v.x); h.y = f2bf(v.y); h.z = f2bf(v.z); h.w = f2bf(v.w);
    dst[i] = h;
}

__global__ __launch_bounds__(256) void prep_kernel(
    const float* __restrict__ state,
    const float* __restrict__ w1, const float* __restrict__ w2,
    const float* __restrict__ w3,
    const float* __restrict__ w11, const float* __restrict__ w21,
    const float* __restrict__ w12, const float* __restrict__ w22,
    const float* __restrict__ b1, const float* __restrict__ b2,
    const float* __restrict__ b3, const float* __restrict__ b11,
    const float* __restrict__ b21, const float* __restrict__ b12,
    const float* __restrict__ b22,
    ushort_t* __restrict__ sh, ushort_t* __restrict__ sl,
    ushort_t* __restrict__ wh123, ushort_t* __restrict__ wl123,
    ushort_t* __restrict__ w1b, ushort_t* __restrict__ w2b,
    float* __restrict__ b123, float* __restrict__ bb1, float* __restrict__ bb2)
{
    const int bid = blockIdx.x;
    const int t = threadIdx.x;
    if (bid < 5120) {
        do_split((const float4*)state, (ushort4*)sh, (ushort4*)sl, bid * 256 + t);
    } else if (bid < 5632) {
        do_split((const float4*)w1, (ushort4*)wh123, (ushort4*)wl123,
                 (bid - 5120) * 256 + t);
    } else if (bid < 6144) {
        do_split((const float4*)w2, (ushort4*)(wh123 + 524288),
                 (ushort4*)(wl123 + 524288), (bid - 5632) * 256 + t);
    } else if (bid < 6656) {
        do_split((const float4*)w3, (ushort4*)(wh123 + 1048576),
                 (ushort4*)(wl123 + 1048576), (bid - 6144) * 256 + t);
    } else if (bid < 10752) {
        do_cvt((const float4*)w11, (ushort4*)w1b, (bid - 6656) * 256 + t);
    } else if (bid < 14848) {
        do_cvt((const float4*)w21, (ushort4*)(w1b + 4194304), (bid - 10752) * 256 + t);
    } else if (bid < 15872) {
        do_cvt((const float4*)w12, (ushort4*)w2b, (bid - 14848) * 256 + t);
    } else if (bid < 16896) {
        do_cvt((const float4*)w22, (ushort4*)(w2b + 1048576), (bid - 15872) * 256 + t);
    } else {
        const int i = (bid - 16896) * 256 + t;
        if (i < 1024) {
            b123[i] = b1[i]; b123[1024 + i] = b2[i]; b123[2048 + i] = b3[i];
            bb1[i] = b11[i]; bb1[1024 + i] = b21[i];
            bb2[i] = b12[i]; bb2[1024 + i] = b22[i];
        }
    }
}

// ---------------------------------------------------------------------------
// Heads (both branches): out[b][n] = (clip?)(h2[b][off+k] . w[n][k] + bias[n])
// grid 512: blocks [0,256) -> mean branch, [256,512) -> log_std branch
// ---------------------------------------------------------------------------
__global__ __launch_bounds__(256) void head_kernel(
    const ushort_t* __restrict__ h, const float* __restrict__ wm,
    const float* __restrict__ bm, const float* __restrict__ ws,
    const float* __restrict__ bs, float* __restrict__ out)
{
    const int t = threadIdx.x;
    const int branch = blockIdx.x >> 8;
    const int n = t & 31;
    const int b = (blockIdx.x & 255) * 8 + (t >> 5);
    const ushort_t* hr = h + (size_t)b * 2048 + branch * 1024;
    const float* wr = (branch ? ws : wm) + (size_t)n * 1024;
    float s = 0.f;
#pragma unroll 4
    for (int k = 0; k < 1024; k += 8) {
        const uint4 hv = *(const uint4*)&hr[k];
        const float4 w0 = *(const float4*)&wr[k];
        const float4 w1 = *(const float4*)&wr[k + 4];
        s += blo(hv.x) * w0.x + bhi(hv.x) * w0.y
           + blo(hv.y) * w0.z + bhi(hv.y) * w0.w
           + blo(hv.z) * w1.x + bhi(hv.z) * w1.y
           + blo(hv.w) * w1.z + bhi(hv.w) * w1.w;
    }
    s += (branch ? bs : bm)[n];
    if (branch) s = fminf(fmaxf(s, -20.f), 2.f);
    out[(size_t)branch * 65536 + (size_t)b * 32 + n] = s;
}

// ---------------------------------------------------------------------------
extern "C" void kernel_launch(void* const* d_in, const int* in_sizes, int n_in,
                              void* d_out, int out_size, void* d_ws, size_t ws_size,
                              hipStream_t stream)
{
    const float* state = (const float*)d_in[0];
    const float* w1  = (const float*)d_in[1];  const float* b1  = (const float*)d_in[2];
    const float* w2  = (const float*)d_in[3];  const float* b2  = (const float*)d_in[4];
    const float* w3  = (const float*)d_in[5];  const float* b3  = (const float*)d_in[6];
    const float* wl  = (const float*)d_in[7];  const float* bl  = (const float*)d_in[8];
    const float* w11 = (const float*)d_in[9];  const float* b11 = (const float*)d_in[10];
    const float* w12 = (const float*)d_in[11]; const float* b12 = (const float*)d_in[12];
    const float* w21 = (const float*)d_in[13]; const float* b21 = (const float*)d_in[14];
    const float* w22 = (const float*)d_in[15]; const float* b22 = (const float*)d_in[16];
    const float* wm  = (const float*)d_in[17]; const float* bm  = (const float*)d_in[18];
    const float* ws  = (const float*)d_in[19]; const float* bs  = (const float*)d_in[20];
    float* out = (float*)d_out;

    // ---- workspace layout (~208 MB) ----
    // cur (125.8 MB) doubles as the split-K partial buffer after recur consumes it
    char* wp = (char*)d_ws;
    float*    cur   = (float*)wp;     wp += (size_t)10240 * 3072 * 4;
    ushort_t* sh    = (ushort_t*)wp;  wp += (size_t)10240 * 512 * 2;
    ushort_t* sl    = (ushort_t*)wp;  wp += (size_t)10240 * 512 * 2;
    ushort_t* wh123 = (ushort_t*)wp;  wp += (size_t)3072 * 512 * 2;
    ushort_t* wl123 = (ushort_t*)wp;  wp += (size_t)3072 * 512 * 2;
    ushort_t* xb    = (ushort_t*)wp;  wp += (size_t)2048 * 4096 * 2;
    ushort_t* w1b   = (ushort_t*)wp;  wp += (size_t)2048 * 4096 * 2;
    ushort_t* w2b   = (ushort_t*)wp;  wp += (size_t)2048 * 1024 * 2;
    ushort_t* h1    = (ushort_t*)wp;  wp += (size_t)2048 * 2048 * 2;
    ushort_t* h2    = (ushort_t*)wp;  wp += (size_t)2048 * 2048 * 2;
    float*    b123  = (float*)wp;     wp += 3072 * 4;
    float*    bb1   = (float*)wp;     wp += 2048 * 4;
    float*    bb2   = (float*)wp;     wp += 2048 * 4;

    const size_t MN = (size_t)2048 * 2048;

    // ---- prep: all splits/cvts/bias packing in one launch ----
    prep_kernel<<<16900, 256, 0, stream>>>(
        state, w1, w2, w3, w11, w21, w12, w22,
        b1, b2, b3, b11, b21, b12, b22,
        sh, sl, wh123, wl123, w1b, w2b, b123, bb1, bb2);

    // ---- currents GEMM (3-term split): [10240,512] x [3072,512]^T -> cur ----
    mfma_gemm512<3><<<dim3(80, 24, 1), 512, 0, stream>>>(
        sh, sl, wh123, wl123, b123, cur, 3072, 512, 512, 512, 3072, 0, 0);

    // ---- recurrence -> x bf16 [2048, 4096] ----
    recur_kernel<<<8192, 256, 0, stream>>>(cur, wl, bl, xb);

    // ---- MLP layer 1 (both branches, N=2048), split-K=4 -> partials in cur ----
    mfma_gemm512<1><<<dim3(16, 16, 4), 512, 0, stream>>>(
        xb, nullptr, w1b, nullptr, nullptr, cur, 2048, 1024, 4096, 4096, 2048, 0, MN);
    reduce_relu<4><<<4096, 256, 0, stream>>>(cur, bb1, h1, 2048, MN);

    // ---- MLP layer 2 (block-diagonal), split-K=2 -> partials in cur ----
    mfma_gemm512<1><<<dim3(16, 16, 2), 512, 0, stream>>>(
        h1, nullptr, w2b, nullptr, nullptr, cur, 2048, 512, 2048, 1024, 2048, 1024, MN);
    reduce_relu<2><<<4096, 256, 0, stream>>>(cur, bb2, h2, 2048, MN);

    // ---- heads (both branches) ----
    head_kernel<<<512, 256, 0, stream>>>(h2, wm, bm, ws, bs, out);
}